// Round 6
// baseline (552.238 us; speedup 1.0000x reference)
//
#include <hip/hip_runtime.h>
#include <hip/hip_cooperative_groups.h>
#include <math.h>

namespace cg = cooperative_groups;

#define NN   1024
#define DD   32
#define EE   32768
#define NBLK 512
#define GRPS (NBLK*8)        // 4096 half-wave groups
#define EPG  (EE/GRPS)       // 8 edges per group

// ---- coop float offsets in ws ----
#define O_EMB  0             // NN*32
#define O_LAMP 32768         // NN*32 (col0 = lam-1)
#define O_PART 65536         // 32*NBLK column partials [col][blk]
#define O_COLS 81920         // 64 (colsum)
#define O_NUMB 81984         // NN*32 (col0 = den)   -- zero region start
#define O_ASUM 114752        // EE*32
#define O_CCNT 1163328       // NN*NN ints (cell counts) -- zero region end
#define O_SLOT 2211904       // NN*NN ints (-1 fill)
#define ZERO_I4 ((O_SLOT-O_NUMB)/4)
#define SLOT_I4 (NN*NN/4)
// ---- fallback extras ----
#define F_SBUF 3260480       // EE*32
#define F_COLS 4309056       // 512 (padded colsum)
#define FZ_I4  ((32768 + EE*32 + EE)/4)   // numb+asum+count zeroed from O_NUMB

__device__ __forceinline__ float artanh_f(float x){
    x = fminf(fmaxf(x, -1.f + 1e-7f), 1.f - 1e-7f);
    return 0.5f * (log1pf(x) - log1pf(-x));
}
__device__ __forceinline__ float arcosh_f(float x){
    x = fmaxf(x, 1.f + 1e-7f);
    return logf(x + sqrtf(x*x - 1.f));
}
__device__ __forceinline__ float rsum(float v){
#pragma unroll
    for (int off=16; off>0; off>>=1) v += __shfl_xor(v, off, 32);
    return v;
}
__device__ __forceinline__ float logmap0_l(float xv, int lane){
    float ss = rsum(lane>=1 ? xv*xv : 0.f);
    float yn = sqrtf(fmaxf(ss, 1e-15f));
    float x0 = __shfl(xv, 0, 32);
    float s  = arcosh_f(x0) / yn;
    return lane>=1 ? s*xv : 0.f;
}
__device__ __forceinline__ float expmap0_proj_l(float uv, int lane){
    float ss = rsum(lane>=1 ? uv*uv : 0.f);
    float xn = sqrtf(fmaxf(ss, 1e-15f));
    float sh = sinhf(xn)/xn;
    float o  = sh*uv;
    float ys = rsum(lane>=1 ? o*o : 0.f);
    float o0 = sqrtf(fmaxf(1.f+ys, 1e-7f));
    return lane==0 ? o0 : o;
}
__device__ __forceinline__ float mobius_add_proj_l(float xv, float yv, int lane){
    float u  = logmap0_l(yv, lane);
    float x1 = lane>=1 ? xv : 0.f;
    float ss = rsum(x1*x1);
    float xn = sqrtf(fmaxf(ss, 1e-15f));
    float alpha = rsum(x1*u) / xn;
    float x0 = __shfl(xv, 0, 32);
    float coef = alpha * (1.f - x0) / xn;
    float w  = lane>=1 ? u - coef*xv : 0.f;
    float ux = rsum(x1*w);
    float w0 = ux / fmaxf(x0, 1e-7f);
    float wsq = rsum(w*w);
    float nu = sqrtf(fmaxf(wsq - w0*w0, 1e-15f));
    float th = fmaxf(nu, 1e-15f);
    float ch = coshf(th), shq = sinhf(th)/th;
    float o  = ch*xv + shq*w;
    float ys = rsum(lane>=1 ? o*o : 0.f);
    float o0 = sqrtf(fmaxf(1.f+ys, 1e-7f));
    return lane==0 ? o0 : o;
}

// shared per-node body: in_emb + lamp
__device__ __forceinline__ void node_body(const float* xs, const float* Wds,
        const float* bd, float* in_emb, float* lamp, int node, int lane, int grp){
    float ssp = 0.f;
#pragma unroll
    for (int r=0;r<4;++r){ int d=lane+32*r; float t=xs[grp*128+d]; if (d>=1) ssp += t*t; }
    float ss = rsum(ssp);
    float yn = sqrtf(fmaxf(ss, 1e-15f));
    float x0 = xs[grp*128];
    float scale = arcosh_f(x0)/yn;
    float acc = 0.f;
    for (int d=1; d<128; ++d) acc += Wds[lane*129+d]*xs[grp*128+d];
    float v = lane>=1 ? acc*scale : 0.f;
    float res = expmap0_proj_l(v, lane);
    float bt  = lane>=1 ? bd[lane] : 0.f;
    float hb  = expmap0_proj_l(bt, lane);
    float o   = mobius_add_proj_l(res, hb, lane);
    in_emb[node*32+lane] = o;
    float o0 = __shfl(o, 0, 32);
    float p  = lane>=1 ? o/(o0+1.f) : 0.f;
    float sq = rsum(p*p);
    float lam = 2.f/fmaxf(1.f-sq, 1e-15f);
    lamp[node*32+lane] = lane>=1 ? lam*p : lam-1.f;
}

// shared per-node epilogue body
__device__ __forceinline__ void out_body(const float* numb, const float* Wos,
        const float* bo, float* out, int i, int lane){
    float nb = numb[i*32+lane];
    float dn = __shfl(nb, 0, 32);
    if (fabsf(dn) < 1e-10f) dn = 1e-10f;
    float g = lane>=1 ? nb/dn : 0.f;
    float gss = rsum(g*g);
    float gn = sqrtf(fmaxf(gss, 1e-15f));
    float scl = tanhf(0.5f*artanh_f(gn))/gn;
    g *= scl;
    float sq = rsum(g*g);
    float dnm = fmaxf(1.f-sq, 1e-15f);
    float h = lane==0 ? (1.f+sq)/dnm : 2.f*g/dnm;
    float r = logmap0_l(h, lane);
    float acc = 0.f;
#pragma unroll
    for (int d=1; d<32; ++d){ float rb = __shfl(r, d, 32); acc += Wos[lane*33+d]*rb; }
    float v = lane>=1 ? acc : 0.f;
    float res = expmap0_proj_l(v, lane);
    float bt  = lane>=1 ? bo[lane] : 0.f;
    float hb  = expmap0_proj_l(bt, lane);
    float o   = mobius_add_proj_l(res, hb, lane);
    out[i*32+lane] = o;
}

// ======================= cooperative fused kernel =======================
__global__ __launch_bounds__(256, 2) void k_fused(
        const float* __restrict__ x, const int* __restrict__ edges,
        const float* __restrict__ Wd, const float* __restrict__ bd,
        const float* __restrict__ Wa, const float* __restrict__ Wo,
        const float* __restrict__ bo, float* __restrict__ out,
        float* __restrict__ ws)
{
    __shared__ float smem[5152];
    cg::grid_group grid = cg::this_grid();
    const int tid = threadIdx.x, lane = tid&31, grp = tid>>5;
    const int bid = blockIdx.x;

    float* in_emb  = ws + O_EMB;
    float* lamp    = ws + O_LAMP;
    float* partial = ws + O_PART;
    float* colsum  = ws + O_COLS;
    float* numb    = ws + O_NUMB;
    float* asum    = ws + O_ASUM;
    int*   cellcnt = (int*)(ws + O_CCNT);
    int*   slotmap = (int*)(ws + O_SLOT);

    // ---- phase A: zero/fill + node embeddings ----
    {
        int4* zb = (int4*)numb;
        int4* sb = (int4*)slotmap;
        int t0 = bid*256 + tid;
        int4 zz; zz.x=0; zz.y=0; zz.z=0; zz.w=0;
        int4 mm; mm.x=-1; mm.y=-1; mm.z=-1; mm.w=-1;
        for (int k=t0; k<ZERO_I4; k+=NBLK*256) zb[k]=zz;
        for (int k=t0; k<SLOT_I4; k+=NBLK*256) sb[k]=mm;
        if (bid < 128){
            float* xs  = smem;
            float* Wds = smem + 1024;
            for (int idx=tid; idx<32*128; idx+=256) Wds[(idx>>7)*129+(idx&127)] = Wd[idx];
            int node = bid*8 + grp;
#pragma unroll
            for (int r=0;r<4;++r) xs[grp*128+lane+32*r] = x[node*128+lane+32*r];
            __syncthreads();
            node_body(xs, Wds, bd, in_emb, lamp, node, lane, grp);
        }
    }
    __threadfence();
    grid.sync();

    // ---- phase B: per-edge logits (es in registers) ----
    float esr[EPG], Br[EPG];
    int   ir[EPG], jr[EPG];
    {
        float* Was  = smem;
        float* cats = smem + 2080;
        float* parts= smem + 2592;
        for (int idx=tid; idx<32*63; idx+=256){ int k=idx/63, c=idx-63*k; Was[k*65+c]=Wa[idx]; }
        __syncthreads();
        int g = bid*8 + grp;
        float colp = 0.f;
#pragma unroll
        for (int k=0;k<EPG;++k){
            int e = g + k*GRPS;
            int i = edges[e], j = edges[EE+e];
            ir[k]=i; jr[k]=j;
            float A = in_emb[i*32+lane], B = in_emb[j*32+lane];
            Br[k]=B;
            float a0 = __shfl(A,0,32)+1.f, b0 = __shfl(B,0,32)+1.f;
            float pa = lane>=1 ? A/a0 : 0.f;
            float pb = lane>=1 ? B/b0 : 0.f;
            float sq = rsum(pa*pa + pb*pb);
            float dnm = fmaxf(1.f-sq, 1e-15f);
            float c0  = (1.f+sq)/dnm;
            float ya = 2.f*pa/dnm, yb = 2.f*pb/dnm;
            float ssy = rsum(ya*ya + yb*yb);
            float ynn = sqrtf(fmaxf(ssy, 1e-15f));
            float sc2 = arcosh_f(c0)/ynn;
            if (lane>=1){ cats[grp*64+lane-1]=ya; cats[grp*64+30+lane]=yb; }
            __syncthreads();
            float acc = 0.f;
            for (int t=0;t<62;++t) acc += Was[lane*65+1+t]*cats[grp*64+t];
            float v = lane>=1 ? acc*sc2 : 0.f;
            float res = expmap0_proj_l(v, lane);
            float r   = logmap0_l(res, lane);
            r = r>=0.f ? r : 0.2f*r;
            float res2 = expmap0_proj_l(r, lane);
            float sv   = logmap0_l(res2, lane);
            float es   = lane>=1 ? expf(sv) : 0.f;
            esr[k] = es;
            colp  += es;
            if (lane==0){
                atomicMax(&slotmap[i*NN+j], e);
                atomicAdd(&cellcnt[i*NN+j], 1);
            }
            __syncthreads();
        }
        parts[grp*32+lane] = colp;
        __syncthreads();
        if (grp==0){
            float s8 = 0.f;
#pragma unroll
            for (int g2=0; g2<8; ++g2) s8 += parts[g2*32+lane];
            partial[lane*NBLK + bid] = s8;
        }
    }
    __threadfence();
    grid.sync();

    // ---- phase B2: reduce partials -> colsum ----
    if (bid < 32){
        float s = 0.f;
#pragma unroll
        for (int r=0;r<NBLK/256;++r) s += partial[bid*NBLK + tid + r*256];
        smem[tid] = s;
        __syncthreads();
        for (int off=128; off>0; off>>=1){
            if (tid<off) smem[tid]+=smem[tid+off];
            __syncthreads();
        }
        if (tid==0) colsum[bid] = smem[0];
    }
    __threadfence();
    grid.sync();

    // ---- phase C: softmax -> a; unique cells inline ----
    int cntr[EPG];
    {
        float csum = lane>=1 ? colsum[lane] : 1.f;
        int g = bid*8 + grp;
#pragma unroll
        for (int k=0;k<EPG;++k){
            int i = ir[k], j = jr[k];
            float u = lane>=1 ? esr[k]/csum : 0.f;
            float a = expmap0_proj_l(u, lane);
            int cnt = cellcnt[i*NN+j];
            cntr[k] = cnt;
            if (cnt == 1){
                float w  = Br[k];
                float ad = __shfl(a,0,32)+1.f;
                float wd = __shfl(w,0,32)+1.f;
                float pa_ = lane>=1 ? a/ad : 0.f;
                float pw  = lane>=1 ? w/wd : 0.f;
                float dot = rsum(pa_*pw);
                float wns = rsum(pw*pw);
                float wn  = sqrtf(fmaxf(wns, 1e-15f));
                float att = tanhf(dot/wn * artanh_f(wn));
                atomicAdd(&numb[i*32+lane], att*lamp[j*32+lane]);
            } else {
                int slot = slotmap[i*NN+j];
                atomicAdd(&asum[slot*32+lane], a);
            }
        }
    }
    __threadfence();
    grid.sync();

    // ---- phase D: duplicate-cell winners ----
    {
        int g = bid*8 + grp;
#pragma unroll
        for (int k=0;k<EPG;++k){
            int e = g + k*GRPS;
            int i = ir[k], j = jr[k];
            if (cntr[k] > 1 && slotmap[i*NN+j] == e){
                float m  = (float)cntr[k];
                float ac = asum[e*32+lane];
                float w  = Br[k];
                float ad = __shfl(ac,0,32)+1.f;
                float wd = m*__shfl(w,0,32)+1.f;
                float pa_ = lane>=1 ? ac/ad : 0.f;
                float pw  = lane>=1 ? m*w/wd : 0.f;
                float dot = rsum(pa_*pw);
                float wns = rsum(pw*pw);
                float wn  = sqrtf(fmaxf(wns, 1e-15f));
                float att = tanhf(dot/wn * artanh_f(wn));
                atomicAdd(&numb[i*32+lane], att*lamp[j*32+lane]);
            }
        }
    }
    __threadfence();
    grid.sync();

    // ---- phase E: per-node epilogue ----
    if (bid < 128){
        float* Wos = smem;
        for (int idx=tid; idx<1024; idx+=256) Wos[(idx>>5)*33+(idx&31)] = Wo[idx];
        __syncthreads();
        out_body(numb, Wos, bo, out, bid*8+grp, lane);
    }
}

// ======================= fallback pipeline (round-4, proven) =======================
__global__ __launch_bounds__(256) void k_init_fb(int4* zb, int4* sb, int4* cb){
    int tid = blockIdx.x*256 + threadIdx.x;
    int nthr = gridDim.x*256;
    int4 zz; zz.x=0; zz.y=0; zz.z=0; zz.w=0;
    int4 mm; mm.x=-1; mm.y=-1; mm.z=-1; mm.w=-1;
    for (int k=tid; k<FZ_I4; k+=nthr) zb[k]=zz;
    for (int k=tid; k<SLOT_I4; k+=nthr) sb[k]=mm;
    if (tid < 128) cb[tid]=zz;
}

__global__ __launch_bounds__(256) void k_node_fb(const float* __restrict__ x,
        const float* __restrict__ Wd, const float* __restrict__ bd,
        float* __restrict__ in_emb, float* __restrict__ lamp){
    __shared__ float xs[8*128];
    __shared__ float Wds[32*129];
    int tid = threadIdx.x, lane = tid&31, grp = tid>>5;
    int node = blockIdx.x*8 + grp;
    for (int idx=tid; idx<32*128; idx+=256) Wds[(idx>>7)*129+(idx&127)] = Wd[idx];
#pragma unroll
    for (int r=0;r<4;++r) xs[grp*128+lane+32*r] = x[node*128 + lane + 32*r];
    __syncthreads();
    node_body(xs, Wds, bd, in_emb, lamp, node, lane, grp);
}

__global__ __launch_bounds__(256) void k_edge_s_fb(const int* __restrict__ edges,
        const float* __restrict__ Wa, const float* __restrict__ in_emb,
        float* __restrict__ sbuf, int* __restrict__ slotmap){
    __shared__ float Was[32*65];
    __shared__ float cats[8*64];
    int tid = threadIdx.x, lane = tid&31, grp = tid>>5;
    int e = blockIdx.x*8 + grp;
    for (int idx=tid; idx<32*63; idx+=256){ int k=idx/63, c=idx-63*k; Was[k*65+c]=Wa[idx]; }
    int i = edges[e], j = edges[EE+e];
    float A = in_emb[i*32+lane], B = in_emb[j*32+lane];
    float a0 = __shfl(A,0,32)+1.f, b0 = __shfl(B,0,32)+1.f;
    float pa = lane>=1 ? A/a0 : 0.f;
    float pb = lane>=1 ? B/b0 : 0.f;
    float sq = rsum(pa*pa + pb*pb);
    float dnm = fmaxf(1.f-sq, 1e-15f);
    float c0  = (1.f+sq)/dnm;
    float ya = 2.f*pa/dnm, yb = 2.f*pb/dnm;
    float ssy = rsum(ya*ya + yb*yb);
    float ynn = sqrtf(fmaxf(ssy, 1e-15f));
    float sc2 = arcosh_f(c0)/ynn;
    if (lane>=1){ cats[grp*64+lane-1]=ya; cats[grp*64+30+lane]=yb; }
    __syncthreads();
    float acc = 0.f;
    for (int t=0;t<62;++t) acc += Was[lane*65+1+t]*cats[grp*64+t];
    float v = lane>=1 ? acc*sc2 : 0.f;
    float res = expmap0_proj_l(v, lane);
    float r   = logmap0_l(res, lane);
    r = r>=0.f ? r : 0.2f*r;
    float res2 = expmap0_proj_l(r, lane);
    float sv   = logmap0_l(res2, lane);
    float es   = lane>=1 ? expf(sv) : 0.f;
    sbuf[e*32+lane] = es;
    if (lane==0) atomicMax(&slotmap[i*NN+j], e);
}

__global__ __launch_bounds__(256) void k_colsum_fb(const float* __restrict__ sbuf,
        float* __restrict__ colsum){
    __shared__ float part[8*32];
    int tid = threadIdx.x, lane = tid&31, grp = tid>>5;
    float acc = 0.f;
    int base = blockIdx.x*256 + grp*32;
#pragma unroll
    for (int it=0; it<32; ++it) acc += sbuf[(base+it)*32 + lane];
    part[grp*32+lane] = acc;
    __syncthreads();
    if (grp==0){
        float s8 = 0.f;
#pragma unroll
        for (int g=0; g<8; ++g) s8 += part[g*32+lane];
        atomicAdd(&colsum[lane*16], s8);
    }
}

__global__ __launch_bounds__(256) void k_edge_a_fb(const int* __restrict__ edges,
        const float* __restrict__ sbuf, const float* __restrict__ colsum,
        const int* __restrict__ slotmap,
        float* __restrict__ asum, int* __restrict__ count){
    int tid = threadIdx.x, lane = tid&31, grp = tid>>5;
    int e = blockIdx.x*8 + grp;
    float es = sbuf[e*32+lane];
    float u = lane>=1 ? es / colsum[lane*16] : 0.f;
    float a = expmap0_proj_l(u, lane);
    int i = edges[e], j = edges[EE+e];
    int slot = slotmap[i*NN+j];
    if (lane==0) atomicAdd(&count[slot], 1);
    atomicAdd(&asum[slot*32+lane], a);
}

__global__ __launch_bounds__(256) void k_cell_fb(const int* __restrict__ edges,
        const int* __restrict__ slotmap, const int* __restrict__ count,
        const float* __restrict__ asum, const float* __restrict__ in_emb,
        const float* __restrict__ lamp, float* __restrict__ numb){
    int tid = threadIdx.x, lane = tid&31, grp = tid>>5;
    int e = blockIdx.x*8 + grp;
    int i = edges[e], j = edges[EE+e];
    if (slotmap[i*NN+j] != e) return;
    float m  = (float)count[e];
    float ac = asum[e*32+lane];
    float w  = in_emb[j*32+lane];
    float ad = __shfl(ac,0,32)+1.f;
    float wd = m*__shfl(w,0,32)+1.f;
    float pa_ = lane>=1 ? ac/ad : 0.f;
    float pw  = lane>=1 ? m*w/wd : 0.f;
    float dot = rsum(pa_*pw);
    float wns = rsum(pw*pw);
    float wn  = sqrtf(fmaxf(wns, 1e-15f));
    float att = tanhf(dot/wn * artanh_f(wn));
    atomicAdd(&numb[i*32+lane], att*lamp[j*32+lane]);
}

__global__ __launch_bounds__(256) void k_out_fb(const float* __restrict__ numb,
        const float* __restrict__ Wo, const float* __restrict__ bo,
        float* __restrict__ out){
    __shared__ float Wos[32*33];
    int tid = threadIdx.x, lane = tid&31, grp = tid>>5;
    for (int idx=tid; idx<1024; idx+=256) Wos[(idx>>5)*33+(idx&31)] = Wo[idx];
    __syncthreads();
    out_body(numb, Wos, bo, out, blockIdx.x*8+grp, lane);
}

extern "C" void kernel_launch(void* const* d_in, const int* in_sizes, int n_in,
                              void* d_out, int out_size, void* d_ws, size_t ws_size,
                              hipStream_t stream) {
    const float* x  = (const float*)d_in[0];
    const int* edges = (const int*)d_in[1];
    const float* Wd = (const float*)d_in[2];
    const float* bd = (const float*)d_in[3];
    const float* Wa = (const float*)d_in[4];
    const float* Wo = (const float*)d_in[5];
    const float* bo = (const float*)d_in[6];
    float* out = (float*)d_out;
    float* f   = (float*)d_ws;

    // host-side occupancy gate (capture-safe, deterministic)
    int occ = 0;
    hipError_t qerr = hipOccupancyMaxActiveBlocksPerMultiprocessor(&occ, k_fused, 256, 0);
    if (qerr == hipSuccess && occ >= 2){
        void* args[] = {(void*)&x, (void*)&edges, (void*)&Wd, (void*)&bd,
                        (void*)&Wa, (void*)&Wo, (void*)&bo, (void*)&out, (void*)&f};
        hipError_t lerr = hipLaunchCooperativeKernel((void*)k_fused, dim3(NBLK), dim3(256),
                                                     args, 0, stream);
        if (lerr == hipSuccess) return;
    }

    // fallback: proven multi-kernel pipeline
    k_init_fb<<<1024, 256, 0, stream>>>((int4*)(f+O_NUMB), (int4*)(f+O_SLOT), (int4*)(f+F_COLS));
    k_node_fb<<<NN/8, 256, 0, stream>>>(x, Wd, bd, f+O_EMB, f+O_LAMP);
    k_edge_s_fb<<<EE/8, 256, 0, stream>>>(edges, Wa, f+O_EMB, f+F_SBUF, (int*)(f+O_SLOT));
    k_colsum_fb<<<128, 256, 0, stream>>>(f+F_SBUF, f+F_COLS);
    k_edge_a_fb<<<EE/8, 256, 0, stream>>>(edges, f+F_SBUF, f+F_COLS, (int*)(f+O_SLOT),
                                          f+O_ASUM, (int*)(f+O_CCNT));
    k_cell_fb<<<EE/8, 256, 0, stream>>>(edges, (int*)(f+O_SLOT), (int*)(f+O_CCNT),
                                        f+O_ASUM, f+O_EMB, f+O_LAMP, f+O_NUMB);
    k_out_fb<<<NN/8, 256, 0, stream>>>(f+O_NUMB, Wo, bo, out);
}

// Round 7
// 79.069 us; speedup vs baseline: 6.9842x; 6.9842x over previous
//
#include <hip/hip_runtime.h>
#include <math.h>

#define NN   1024
#define DD   32
#define EE   32768

// ---- workspace float offsets ----
#define O_EMB  0             // NN*32
#define O_LAMP 32768         // NN*32 (col0 = lam-1)
#define O_PART 65536         // 4096*32 colsum partials [blk][col]
#define O_COLS 196608        // 64
#define O_NUMB 196672        // NN*32 (col0 = den)   -- zero region start
#define O_ASUM 229440        // EE*32
#define O_CCNT 1278016       // NN*NN ints
#define O_NDUP 2326592       // 16 ints              -- zero region end
#define O_SLOT 2326608       // NN*NN ints (-1 fill)
#define O_DUPL 3375184       // 32768 ints (no init needed)
#define ZERO_I4 ((O_SLOT - O_NUMB)/4)
#define SLOT_I4 (NN*NN/4)

__device__ __forceinline__ float artanh_f(float x){
    x = fminf(fmaxf(x, -1.f + 1e-7f), 1.f - 1e-7f);
    return 0.5f * (log1pf(x) - log1pf(-x));
}
__device__ __forceinline__ float arcosh_f(float x){
    x = fmaxf(x, 1.f + 1e-7f);
    return logf(x + sqrtf(x*x - 1.f));
}
__device__ __forceinline__ float rsum(float v){
#pragma unroll
    for (int off=16; off>0; off>>=1) v += __shfl_xor(v, off, 32);
    return v;
}
__device__ __forceinline__ float logmap0_l(float xv, int lane){
    float ss = rsum(lane>=1 ? xv*xv : 0.f);
    float yn = sqrtf(fmaxf(ss, 1e-15f));
    float x0 = __shfl(xv, 0, 32);
    float s  = arcosh_f(x0) / yn;
    return lane>=1 ? s*xv : 0.f;
}
__device__ __forceinline__ float expmap0_proj_l(float uv, int lane){
    float ss = rsum(lane>=1 ? uv*uv : 0.f);
    float xn = sqrtf(fmaxf(ss, 1e-15f));
    float sh = sinhf(xn)/xn;
    float o  = sh*uv;
    float ys = rsum(lane>=1 ? o*o : 0.f);
    float o0 = sqrtf(fmaxf(1.f+ys, 1e-7f));
    return lane==0 ? o0 : o;
}
__device__ __forceinline__ float mobius_add_proj_l(float xv, float yv, int lane){
    float u  = logmap0_l(yv, lane);
    float x1 = lane>=1 ? xv : 0.f;
    float ss = rsum(x1*x1);
    float xn = sqrtf(fmaxf(ss, 1e-15f));
    float alpha = rsum(x1*u) / xn;
    float x0 = __shfl(xv, 0, 32);
    float coef = alpha * (1.f - x0) / xn;
    float w  = lane>=1 ? u - coef*xv : 0.f;
    float ux = rsum(x1*w);
    float w0 = ux / fmaxf(x0, 1e-7f);
    float wsq = rsum(w*w);
    float nu = sqrtf(fmaxf(wsq - w0*w0, 1e-15f));
    float th = fmaxf(nu, 1e-15f);
    float ch = coshf(th), shq = sinhf(th)/th;
    float o  = ch*xv + shq*w;
    float ys = rsum(lane>=1 ? o*o : 0.f);
    float o0 = sqrtf(fmaxf(1.f+ys, 1e-7f));
    return lane==0 ? o0 : o;
}

// per-edge att for a cell with accumulated a (ac) and multiplicity m
__device__ __forceinline__ float att_of(float ac, float w, float m, int lane){
    float ad = __shfl(ac,0,32)+1.f;
    float wd = m*__shfl(w,0,32)+1.f;
    float pa_ = lane>=1 ? ac/ad : 0.f;
    float pw  = lane>=1 ? m*w/wd : 0.f;
    float dot = rsum(pa_*pw);
    float wns = rsum(pw*pw);
    float wn  = sqrtf(fmaxf(wns, 1e-15f));
    return tanhf(dot/wn * artanh_f(wn));
}

// ---- A: workspace init + per-node embeddings (independent; merged) ----
__global__ __launch_bounds__(256) void k_a(const float* __restrict__ x,
        const float* __restrict__ Wd, const float* __restrict__ bd,
        float* __restrict__ ws){
    __shared__ float smem[5152];     // xs[8*128] + Wds[32*129]
    int tid = threadIdx.x, lane = tid&31, grp = tid>>5, bid = blockIdx.x;
    {   // zero / fill
        int4* zb = (int4*)(ws + O_NUMB);
        int4* sb = (int4*)(ws + O_SLOT);
        int t0 = bid*256 + tid, nthr = gridDim.x*256;
        int4 zz; zz.x=0; zz.y=0; zz.z=0; zz.w=0;
        int4 mm; mm.x=-1; mm.y=-1; mm.z=-1; mm.w=-1;
        for (int k=t0; k<ZERO_I4; k+=nthr) zb[k]=zz;
        for (int k=t0; k<SLOT_I4; k+=nthr) sb[k]=mm;
    }
    if (bid < 128){
        float* xs  = smem;           // [8][128]
        float* Wds = smem + 1024;    // [32][129]
        float* in_emb = ws + O_EMB;
        float* lamp   = ws + O_LAMP;
        for (int idx=tid; idx<32*128; idx+=256) Wds[(idx>>7)*129+(idx&127)] = Wd[idx];
        int node = bid*8 + grp;
#pragma unroll
        for (int r=0;r<4;++r) xs[grp*128+lane+32*r] = x[node*128+lane+32*r];
        __syncthreads();
        float ssp = 0.f;
#pragma unroll
        for (int r=0;r<4;++r){ int d=lane+32*r; float t=xs[grp*128+d]; if (d>=1) ssp += t*t; }
        float ss = rsum(ssp);
        float yn = sqrtf(fmaxf(ss, 1e-15f));
        float x0 = xs[grp*128];
        float scale = arcosh_f(x0)/yn;
        float acc = 0.f;
        for (int d=1; d<128; ++d) acc += Wds[lane*129+d]*xs[grp*128+d];
        float v = lane>=1 ? acc*scale : 0.f;
        float res = expmap0_proj_l(v, lane);
        float bt  = lane>=1 ? bd[lane] : 0.f;
        float hb  = expmap0_proj_l(bt, lane);
        float o   = mobius_add_proj_l(res, hb, lane);
        in_emb[node*32+lane] = o;
        float o0 = __shfl(o, 0, 32);
        float p  = lane>=1 ? o/(o0+1.f) : 0.f;
        float sq = rsum(p*p);
        float lam = 2.f/fmaxf(1.f-sq, 1e-15f);
        lamp[node*32+lane] = lane>=1 ? lam*p : lam-1.f;
    }
}

// ---- B: per-edge logits es; claim slot; count cell; per-block col partials ----
__global__ __launch_bounds__(256) void k_b(const int* __restrict__ edges,
        const float* __restrict__ Wa, float* __restrict__ ws){
    __shared__ float Was[32*65];
    __shared__ float cats[8*64];
    __shared__ float parts[8*32];
    const float* in_emb = ws + O_EMB;
    float* sbuf    = ws + O_ASUM;      // reuse asum region? NO -- separate: see note
    // NOTE: sbuf must not alias asum (both used in D). sbuf lives in partials? no.
    // sbuf = es per edge stored where asum zeroing won't clobber: use dedicated region.
    sbuf = ws + O_DUPL + 32768;        // EE*32 after duplist
    int* slotmap = (int*)(ws + O_SLOT);
    int* cellcnt = (int*)(ws + O_CCNT);
    float* partial = ws + O_PART;
    int tid = threadIdx.x, lane = tid&31, grp = tid>>5;
    int e = blockIdx.x*8 + grp;
    for (int idx=tid; idx<32*63; idx+=256){ int k=idx/63, c=idx-63*k; Was[k*65+c]=Wa[idx]; }
    int i = edges[e], j = edges[EE+e];
    float A = in_emb[i*32+lane], B = in_emb[j*32+lane];
    float a0 = __shfl(A,0,32)+1.f, b0 = __shfl(B,0,32)+1.f;
    float pa = lane>=1 ? A/a0 : 0.f;
    float pb = lane>=1 ? B/b0 : 0.f;
    float sq = rsum(pa*pa + pb*pb);
    float dnm = fmaxf(1.f-sq, 1e-15f);
    float c0  = (1.f+sq)/dnm;
    float ya = 2.f*pa/dnm, yb = 2.f*pb/dnm;
    float ssy = rsum(ya*ya + yb*yb);
    float ynn = sqrtf(fmaxf(ssy, 1e-15f));
    float sc2 = arcosh_f(c0)/ynn;
    if (lane>=1){ cats[grp*64+lane-1]=ya; cats[grp*64+30+lane]=yb; }
    __syncthreads();
    float acc = 0.f;
    for (int t=0;t<62;++t) acc += Was[lane*65+1+t]*cats[grp*64+t];
    float v = lane>=1 ? acc*sc2 : 0.f;
    float res = expmap0_proj_l(v, lane);
    float r   = logmap0_l(res, lane);
    r = r>=0.f ? r : 0.2f*r;                 // leaky_relu
    float res2 = expmap0_proj_l(r, lane);
    float sv   = logmap0_l(res2, lane);
    float es   = lane>=1 ? expf(sv) : 0.f;   // logits bounded: no max pass needed
    sbuf[e*32+lane] = es;
    if (lane==0){
        atomicMax(&slotmap[i*NN+j], e);
        atomicAdd(&cellcnt[i*NN+j], 1);
    }
    parts[grp*32+lane] = es;
    __syncthreads();
    if (grp==0){
        float s8 = 0.f;
#pragma unroll
        for (int g=0; g<8; ++g) s8 += parts[g*32+lane];
        partial[blockIdx.x*32+lane] = s8;    // coalesced, racefree
    }
}

// ---- C: reduce 4096 partials per column -> colsum ----
__global__ __launch_bounds__(256) void k_c(float* __restrict__ ws){
    __shared__ float red[256];
    const float* partial = ws + O_PART;
    float* colsum = ws + O_COLS;
    int tid = threadIdx.x, col = blockIdx.x;
    float s = 0.f;
    for (int k=tid; k<4096; k+=256) s += partial[k*32+col];
    red[tid]=s; __syncthreads();
    for (int off=128; off>0; off>>=1){
        if (tid<off) red[tid]+=red[tid+off];
        __syncthreads();
    }
    if (tid==0) colsum[col]=red[0];
}

// ---- D: softmax -> a; unique cells inline; dup deposits + duplist ----
__global__ __launch_bounds__(256) void k_d(const int* __restrict__ edges,
        float* __restrict__ ws){
    const float* sbuf   = ws + O_DUPL + 32768;
    const float* colsum = ws + O_COLS;
    const float* in_emb = ws + O_EMB;
    const float* lamp   = ws + O_LAMP;
    float* numb   = ws + O_NUMB;
    float* asum   = ws + O_ASUM;
    int* slotmap  = (int*)(ws + O_SLOT);
    int* cellcnt  = (int*)(ws + O_CCNT);
    int* ndup     = (int*)(ws + O_NDUP);
    int* duplist  = (int*)(ws + O_DUPL);
    int tid = threadIdx.x, lane = tid&31, grp = tid>>5;
    int e = blockIdx.x*8 + grp;
    int i = edges[e], j = edges[EE+e];
    float es = sbuf[e*32+lane];
    float csum = lane>=1 ? colsum[lane] : 1.f;
    float u = lane>=1 ? es/csum : 0.f;
    float a = expmap0_proj_l(u, lane);
    int cnt = cellcnt[i*NN+j];
    if (cnt == 1){
        float w = in_emb[j*32+lane];
        float att = att_of(a, w, 1.f, lane);
        atomicAdd(&numb[i*32+lane], att*lamp[j*32+lane]);
    } else {
        int slot = slotmap[i*NN+j];
        atomicAdd(&asum[slot*32+lane], a);
        if (lane==0 && slot==e){            // winner builds compact dup list
            int t = atomicAdd(ndup, 1);
            duplist[t] = e;
        }
    }
}

// ---- E: duplicate-cell winners (grid-stride over duplist) ----
__global__ __launch_bounds__(256) void k_e(const int* __restrict__ edges,
        float* __restrict__ ws){
    const float* asum   = ws + O_ASUM;
    const float* in_emb = ws + O_EMB;
    const float* lamp   = ws + O_LAMP;
    float* numb  = ws + O_NUMB;
    int* cellcnt = (int*)(ws + O_CCNT);
    int* ndup    = (int*)(ws + O_NDUP);
    int* duplist = (int*)(ws + O_DUPL);
    int tid = threadIdx.x, lane = tid&31;
    int gid = (blockIdx.x*256 + tid) >> 5;     // 64 groups
    int n = *ndup;
    for (int idx=gid; idx<n; idx+=64){
        int e = duplist[idx];
        int i = edges[e], j = edges[EE+e];
        float m  = (float)cellcnt[i*NN+j];
        float ac = asum[e*32+lane];
        float w  = in_emb[j*32+lane];
        float att = att_of(ac, w, m, lane);
        atomicAdd(&numb[i*32+lane], att*lamp[j*32+lane]);
    }
}

// ---- F: per-node epilogue ----
__global__ __launch_bounds__(256) void k_f(const float* __restrict__ Wo,
        const float* __restrict__ bo, float* __restrict__ out,
        float* __restrict__ ws){
    __shared__ float Wos[32*33];
    const float* numb = ws + O_NUMB;
    int tid = threadIdx.x, lane = tid&31, grp = tid>>5;
    int i = blockIdx.x*8 + grp;
    for (int idx=tid; idx<1024; idx+=256) Wos[(idx>>5)*33+(idx&31)] = Wo[idx];
    __syncthreads();
    float nb = numb[i*32+lane];
    float dn = __shfl(nb, 0, 32);
    if (fabsf(dn) < 1e-10f) dn = 1e-10f;
    float g = lane>=1 ? nb/dn : 0.f;
    float gss = rsum(g*g);
    float gn = sqrtf(fmaxf(gss, 1e-15f));
    float scl = tanhf(0.5f*artanh_f(gn))/gn;
    g *= scl;
    float sq = rsum(g*g);
    float dnm = fmaxf(1.f-sq, 1e-15f);
    float h = lane==0 ? (1.f+sq)/dnm : 2.f*g/dnm;
    float r = logmap0_l(h, lane);
    float acc = 0.f;
#pragma unroll
    for (int d=1; d<32; ++d){ float rb = __shfl(r, d, 32); acc += Wos[lane*33+d]*rb; }
    float v = lane>=1 ? acc : 0.f;
    float res = expmap0_proj_l(v, lane);
    float bt  = lane>=1 ? bo[lane] : 0.f;
    float hb  = expmap0_proj_l(bt, lane);
    float o   = mobius_add_proj_l(res, hb, lane);
    out[i*32+lane] = o;
}

extern "C" void kernel_launch(void* const* d_in, const int* in_sizes, int n_in,
                              void* d_out, int out_size, void* d_ws, size_t ws_size,
                              hipStream_t stream) {
    const float* x  = (const float*)d_in[0];
    const int* edges = (const int*)d_in[1];
    const float* Wd = (const float*)d_in[2];
    const float* bd = (const float*)d_in[3];
    const float* Wa = (const float*)d_in[4];
    const float* Wo = (const float*)d_in[5];
    const float* bo = (const float*)d_in[6];
    float* out = (float*)d_out;
    float* ws  = (float*)d_ws;

    k_a<<<1024, 256, 0, stream>>>(x, Wd, bd, ws);
    k_b<<<EE/8, 256, 0, stream>>>(edges, Wa, ws);
    k_c<<<32,   256, 0, stream>>>(ws);
    k_d<<<EE/8, 256, 0, stream>>>(edges, ws);
    k_e<<<8,    256, 0, stream>>>(edges, ws);
    k_f<<<NN/8, 256, 0, stream>>>(Wo, bo, out, ws);
}

// Round 8
// 60.534 us; speedup vs baseline: 9.1228x; 1.3062x over previous
//
#include <hip/hip_runtime.h>
#include <math.h>

#define NN   1024
#define DD   32
#define EE   32768

// ---- workspace float offsets ----
#define O_EMB  0             // NN*32  in_emb (hyperboloid)  [k_e only]
#define O_LAMP 32768         // NN*32  lamp: lane0=lam-1, 1..31=lam*p
#define O_PARR 65536         // NN*32  parr: lane0=artanh(wn)/wn, 1..31=p_in
#define O_PN2  98304         // NN     |p_in|^2
#define O_PART 99328         // 1024*32 colsum partials [blk][col]
#define O_COLS 132096        // 64
#define O_NUMB 132160        // NN*32 (col0=den)      -- zero region start
#define O_ASUM 164928        // EE*32
#define O_CCNT 1213504       // NN*NN ints
#define O_NDUP 2262080       // 16 ints               -- zero region end
#define O_SLOT 2262096       // NN*NN ints (-1 fill)
#define O_DUPL 3310672       // EE ints (no init)
#define O_SBUF 3343440       // EE*32 es values
#define ZERO_I4 ((O_SLOT - O_NUMB)/4)   // 532484
#define SLOT_I4 (NN*NN/4)               // 262144

__device__ __forceinline__ float artanh_f(float x){
    x = fminf(fmaxf(x, -1.f + 1e-7f), 1.f - 1e-7f);
    return 0.5f * (log1pf(x) - log1pf(-x));
}
__device__ __forceinline__ float arcosh_f(float x){
    x = fmaxf(x, 1.f + 1e-7f);
    return logf(x + sqrtf(x*x - 1.f));
}
__device__ __forceinline__ float rsum(float v){
#pragma unroll
    for (int off=16; off>0; off>>=1) v += __shfl_xor(v, off, 32);
    return v;
}
__device__ __forceinline__ float logmap0_l(float xv, int lane){
    float ss = rsum(lane>=1 ? xv*xv : 0.f);
    float yn = sqrtf(fmaxf(ss, 1e-15f));
    float x0 = __shfl(xv, 0, 32);
    float s  = arcosh_f(x0) / yn;
    return lane>=1 ? s*xv : 0.f;
}
__device__ __forceinline__ float expmap0_proj_l(float uv, int lane){
    float ss = rsum(lane>=1 ? uv*uv : 0.f);
    float xn = sqrtf(fmaxf(ss, 1e-15f));
    float sh = sinhf(xn)/xn;
    float o  = sh*uv;
    float ys = rsum(lane>=1 ? o*o : 0.f);
    float o0 = sqrtf(fmaxf(1.f+ys, 1e-7f));
    return lane==0 ? o0 : o;
}
// h_proj(h_mobius_add) with tangent u given DIRECTLY (logmap0(expmap0(b)) == b)
__device__ __forceinline__ float mobius_add_u_l(float xv, float uv, int lane){
    float u  = lane>=1 ? uv : 0.f;
    float x1 = lane>=1 ? xv : 0.f;
    float ss = rsum(x1*x1);
    float xn = sqrtf(fmaxf(ss, 1e-15f));
    float alpha = rsum(x1*u) / xn;
    float x0 = __shfl(xv, 0, 32);
    float coef = alpha * (1.f - x0) / xn;
    float w  = lane>=1 ? u - coef*xv : 0.f;
    float ux = rsum(x1*w);
    float w0 = ux / fmaxf(x0, 1e-7f);
    float wsq = rsum(w*w);
    float nu = sqrtf(fmaxf(wsq - w0*w0, 1e-15f));
    float th = fmaxf(nu, 1e-15f);
    float ch = coshf(th), shq = sinhf(th)/th;
    float o  = ch*xv + shq*w;
    float ys = rsum(lane>=1 ? o*o : 0.f);
    float o0 = sqrtf(fmaxf(1.f+ys, 1e-7f));
    return lane==0 ? o0 : o;
}
// full att for dup cells (accumulated ac, multiplicity m)
__device__ __forceinline__ float att_of(float ac, float w, float m, int lane){
    float ad = __shfl(ac,0,32)+1.f;
    float wd = m*__shfl(w,0,32)+1.f;
    float pa_ = lane>=1 ? ac/ad : 0.f;
    float pw  = lane>=1 ? m*w/wd : 0.f;
    float dot = rsum(pa_*pw);
    float wns = rsum(pw*pw);
    float wn  = sqrtf(fmaxf(wns, 1e-15f));
    return tanhf(dot/wn * artanh_f(wn));
}

// ---- A: fill (blocks 128..1023) + per-node precompute (blocks 0..127) ----
__global__ __launch_bounds__(256) void k_a(const float* __restrict__ x,
        const float* __restrict__ Wd, const float* __restrict__ bd,
        float* __restrict__ ws){
    __shared__ float smem[5152];
    int tid = threadIdx.x, lane = tid&31, grp = tid>>5, bid = blockIdx.x;
    if (bid >= 128){
        int4* zb = (int4*)(ws + O_NUMB);
        int4* sb = (int4*)(ws + O_SLOT);
        int t0 = (bid-128)*256 + tid, nthr = 896*256;
        int4 zz; zz.x=0; zz.y=0; zz.z=0; zz.w=0;
        int4 mm; mm.x=-1; mm.y=-1; mm.z=-1; mm.w=-1;
        for (int k=t0; k<ZERO_I4; k+=nthr) zb[k]=zz;
        for (int k=t0; k<SLOT_I4; k+=nthr) sb[k]=mm;
        return;
    }
    float* xs  = smem;           // [8][128]
    float* Wds = smem + 1024;    // [32][129]
    float* in_emb = ws + O_EMB;
    float* lamp   = ws + O_LAMP;
    float* parr   = ws + O_PARR;
    float* pn2    = ws + O_PN2;
    for (int idx=tid; idx<32*128; idx+=256) Wds[(idx>>7)*129+(idx&127)] = Wd[idx];
    int node = bid*8 + grp;
#pragma unroll
    for (int r=0;r<4;++r) xs[grp*128+lane+32*r] = x[node*128+lane+32*r];
    __syncthreads();
    float ssp = 0.f;
#pragma unroll
    for (int r=0;r<4;++r){ int d=lane+32*r; float t=xs[grp*128+d]; if (d>=1) ssp += t*t; }
    float ss = rsum(ssp);
    float yn = sqrtf(fmaxf(ss, 1e-15f));
    float x0 = xs[grp*128];
    float scale = arcosh_f(x0)/yn;             // logmap0 scale
    float acc = 0.f;
    for (int d=1; d<128; ++d) acc += Wds[lane*129+d]*xs[grp*128+d];
    float v = lane>=1 ? acc*scale : 0.f;
    float res = expmap0_proj_l(v, lane);
    float o   = mobius_add_u_l(res, bd[lane], lane);   // u = bd directly (identity)
    in_emb[node*32+lane] = o;
    float o0 = __shfl(o, 0, 32);
    float p  = lane>=1 ? o/(o0+1.f) : 0.f;     // p_in
    float sq = rsum(p*p);
    float lam = 2.f/fmaxf(1.f-sq, 1e-15f);
    lamp[node*32+lane] = lane>=1 ? lam*p : lam-1.f;
    float wn = sqrtf(fmaxf(sq, 1e-15f));
    float attw = artanh_f(wn)/wn;
    parr[node*32+lane] = lane>=1 ? p : attw;
    if (lane==0) pn2[node] = sq;
}

// ---- B: per-edge logits es = exp(leaky(sc2 * Wa.cat)); slot claim; partials ----
__global__ __launch_bounds__(256) void k_b(const int* __restrict__ edges,
        const float* __restrict__ Wa, float* __restrict__ ws){
    __shared__ float Was[32*65];
    __shared__ float cats[8*64];
    __shared__ float parts[8*32];
    const float* parr = ws + O_PARR;
    const float* pn2  = ws + O_PN2;
    float* sbuf    = ws + O_SBUF;
    float* partial = ws + O_PART;
    int* slotmap = (int*)(ws + O_SLOT);
    int* cellcnt = (int*)(ws + O_CCNT);
    int tid = threadIdx.x, lane = tid&31, grp = tid>>5, bid = blockIdx.x;
    for (int idx=tid; idx<32*63; idx+=256){ int k=idx/63, c=idx-63*k; Was[k*65+c]=Wa[idx]; }
    __syncthreads();
    float colp = 0.f;
#pragma unroll
    for (int k=0;k<4;++k){
        int e = bid*32 + k*8 + grp;
        int i = edges[e], j = edges[EE+e];
        float pi = lane>=1 ? parr[i*32+lane] : 0.f;
        float pj = lane>=1 ? parr[j*32+lane] : 0.f;
        float sq = pn2[i] + pn2[j];
        float dnm = fmaxf(1.f-sq, 1e-15f);
        float c0  = (1.f+sq)/dnm;
        float ssy = 4.f*sq/(dnm*dnm);
        float ynn = sqrtf(fmaxf(ssy, 1e-15f));
        float sc2 = arcosh_f(c0)/ynn;
        float t2 = 2.f/dnm;
        if (lane>=1){ cats[grp*64+lane-1]=t2*pi; cats[grp*64+30+lane]=t2*pj; }
        __syncthreads();
        float acc = 0.f;
        for (int t=0;t<62;++t) acc += Was[lane*65+1+t]*cats[grp*64+t];
        float v = acc*sc2;
        v = v>=0.f ? v : 0.2f*v;                     // leaky (logmap/expmap cancel)
        float es = lane>=1 ? expf(v) : 0.f;          // bounded logits: no max pass
        sbuf[e*32+lane] = es;
        colp += es;
        if (lane==0){
            atomicMax(&slotmap[i*NN+j], e);
            atomicAdd(&cellcnt[i*NN+j], 1);
        }
        __syncthreads();
    }
    parts[grp*32+lane] = colp;
    __syncthreads();
    if (grp==0){
        float s8 = 0.f;
#pragma unroll
        for (int g=0; g<8; ++g) s8 += parts[g*32+lane];
        partial[bid*32+lane] = s8;                   // coalesced, racefree
    }
}

// ---- C: reduce 1024 partials/column -> colsum ----
__global__ __launch_bounds__(256) void k_c(float* __restrict__ ws){
    __shared__ float red[256];
    const float* partial = ws + O_PART;
    float* colsum = ws + O_COLS;
    int tid = threadIdx.x, col = blockIdx.x;
    float s = 0.f;
#pragma unroll
    for (int r=0;r<4;++r) s += partial[(tid + r*256)*32 + col];
    red[tid]=s; __syncthreads();
    for (int off=128; off>0; off>>=1){
        if (tid<off) red[tid]+=red[tid+off];
        __syncthreads();
    }
    if (tid==0) colsum[col]=red[0];
}

// ---- D: softmax; unique cells closed-form att; dup deposits + duplist ----
__global__ __launch_bounds__(256) void k_d(const int* __restrict__ edges,
        float* __restrict__ ws){
    const float* sbuf   = ws + O_SBUF;
    const float* colsum = ws + O_COLS;
    const float* parr   = ws + O_PARR;
    const float* lamp   = ws + O_LAMP;
    float* numb   = ws + O_NUMB;
    float* asum   = ws + O_ASUM;
    int* slotmap  = (int*)(ws + O_SLOT);
    int* cellcnt  = (int*)(ws + O_CCNT);
    int* ndup     = (int*)(ws + O_NDUP);
    int* duplist  = (int*)(ws + O_DUPL);
    int tid = threadIdx.x, lane = tid&31, grp = tid>>5, bid = blockIdx.x;
    float csum = lane>=1 ? colsum[lane] : 1.f;
#pragma unroll
    for (int k=0;k<4;++k){
        int e = bid*32 + k*8 + grp;
        int i = edges[e], j = edges[EE+e];
        float es = sbuf[e*32+lane];
        float u = lane>=1 ? es/csum : 0.f;
        int cnt = cellcnt[i*NN+j];
        if (cnt == 1){
            // p_a = tanh(th/2)/th * u ; att = tanh(dot * artanh(wn_j)/wn_j)
            float th2 = rsum(u*u);
            float th = sqrtf(fmaxf(th2, 1e-15f));
            float f = tanhf(0.5f*th)/th;
            float pj = parr[j*32+lane];
            float attw = __shfl(pj, 0, 32);
            float dotu = rsum(lane>=1 ? u*pj : 0.f);
            float att = tanhf(f*dotu*attw);
            atomicAdd(&numb[i*32+lane], att*lamp[j*32+lane]);
        } else {
            float a = expmap0_proj_l(u, lane);
            int slot = slotmap[i*NN+j];
            atomicAdd(&asum[slot*32+lane], a);
            if (lane==0 && slot==e){
                int t = atomicAdd(ndup, 1);
                duplist[t] = e;
            }
        }
    }
}

// ---- E: duplicate-cell winners ----
__global__ __launch_bounds__(256) void k_e(const int* __restrict__ edges,
        float* __restrict__ ws){
    const float* asum   = ws + O_ASUM;
    const float* in_emb = ws + O_EMB;
    const float* lamp   = ws + O_LAMP;
    float* numb  = ws + O_NUMB;
    int* cellcnt = (int*)(ws + O_CCNT);
    int* ndup    = (int*)(ws + O_NDUP);
    int* duplist = (int*)(ws + O_DUPL);
    int tid = threadIdx.x, lane = tid&31;
    int gid = (blockIdx.x*256 + tid) >> 5;   // 64 groups
    int n = *ndup;
    for (int idx=gid; idx<n; idx+=64){
        int e = duplist[idx];
        int i = edges[e], j = edges[EE+e];
        float m  = (float)cellcnt[i*NN+j];
        float ac = asum[e*32+lane];
        float w  = in_emb[j*32+lane];
        float att = att_of(ac, w, m, lane);
        atomicAdd(&numb[i*32+lane], att*lamp[j*32+lane]);
    }
}

// ---- F: per-node epilogue ----
__global__ __launch_bounds__(256) void k_f(const float* __restrict__ Wo,
        const float* __restrict__ bo, float* __restrict__ out,
        float* __restrict__ ws){
    __shared__ float Wos[32*33];
    const float* numb = ws + O_NUMB;
    int tid = threadIdx.x, lane = tid&31, grp = tid>>5;
    int i = blockIdx.x*8 + grp;
    for (int idx=tid; idx<1024; idx+=256) Wos[(idx>>5)*33+(idx&31)] = Wo[idx];
    __syncthreads();
    float nb = numb[i*32+lane];
    float dn = __shfl(nb, 0, 32);
    if (fabsf(dn) < 1e-10f) dn = 1e-10f;
    float g = lane>=1 ? nb/dn : 0.f;
    float gss = rsum(g*g);
    float gn = sqrtf(fmaxf(gss, 1e-15f));
    float scl = tanhf(0.5f*artanh_f(gn))/gn;
    g *= scl;                                   // p_out
    float sq = rsum(g*g);
    float dnm = fmaxf(1.f-sq, 1e-15f);
    float h = lane==0 ? (1.f+sq)/dnm : 2.f*g/dnm;
    float r = logmap0_l(h, lane);
    float acc = 0.f;
#pragma unroll
    for (int d=1; d<32; ++d){ float rb = __shfl(r, d, 32); acc += Wos[lane*33+d]*rb; }
    float v = lane>=1 ? acc : 0.f;
    float res = expmap0_proj_l(v, lane);
    float o   = mobius_add_u_l(res, bo[lane], lane);  // u = bo directly (identity)
    out[i*32+lane] = o;
}

extern "C" void kernel_launch(void* const* d_in, const int* in_sizes, int n_in,
                              void* d_out, int out_size, void* d_ws, size_t ws_size,
                              hipStream_t stream) {
    const float* x  = (const float*)d_in[0];
    const int* edges = (const int*)d_in[1];
    const float* Wd = (const float*)d_in[2];
    const float* bd = (const float*)d_in[3];
    const float* Wa = (const float*)d_in[4];
    const float* Wo = (const float*)d_in[5];
    const float* bo = (const float*)d_in[6];
    float* out = (float*)d_out;
    float* ws  = (float*)d_ws;

    k_a<<<1024, 256, 0, stream>>>(x, Wd, bd, ws);
    k_b<<<1024, 256, 0, stream>>>(edges, Wa, ws);
    k_c<<<32,   256, 0, stream>>>(ws);
    k_d<<<1024, 256, 0, stream>>>(edges, ws);
    k_e<<<8,    256, 0, stream>>>(edges, ws);
    k_f<<<NN/8, 256, 0, stream>>>(Wo, bo, out, ws);
}